// Round 17
// baseline (316.334 us; speedup 1.0000x reference)
//
#include <hip/hip_runtime.h>

#define N_NODES 20000
#define D_FEAT 256
#define N_SUPPORT 3
#define N_EDGES 320000
#define OUT_DIM 256
#define TOTAL_E (N_SUPPORT * N_EDGES)
#define CAP 64                      // per-(s,dst) bucket; mean 16, P(>64) ~ 1e-9
#define KDIM (N_SUPPORT * D_FEAT)   // 768
#define NBUCKET (N_SUPPORT * N_NODES)
#define GM_ROWS 128
#define GM_BLOCKS ((N_NODES + GM_ROWS - 1) / GM_ROWS)   // 157

// binning
#define NBIN 250                    // dst bins of 80 nodes
#define BINW 80
#define LCAP 30                     // LDS slots per bin per 4096-edge batch (mean 16.4)
#define BINCAP 4608                 // global bin capacity (mean 3840, +12 sigma)
#define PA_BATCH 4096
#define PA_BLOCKS ((TOTAL_E + PA_BATCH - 1) / PA_BATCH)  // 235

typedef __attribute__((ext_vector_type(8))) short short8;
typedef __attribute__((ext_vector_type(8))) unsigned short ushort8;
typedef __attribute__((ext_vector_type(4))) float f32x4;

__device__ inline unsigned short f2bf(float f) {
    unsigned int u = __float_as_uint(f);
    u += 0x7fff + ((u >> 16) & 1);  // round-to-nearest-even
    return (unsigned short)(u >> 16);
}

// ---------------- prep1: quantize_x | convert_w (unchanged, verified) ----------------
#define NB_X (N_NODES / 4)
#define NB_W (N_SUPPORT * D_FEAT)

__global__ void __launch_bounds__(256) prep1(const float* __restrict__ x, const float* __restrict__ W,
        unsigned int* __restrict__ xq, float* __restrict__ scl, unsigned short* __restrict__ wt) {
    const int bid = blockIdx.x;
    const int tid = threadIdx.x;
    if (bid < NB_X) {
        const int row = bid * 4 + (tid >> 6);
        const int lane = tid & 63;
        float4 v = ((const float4*)x)[row * 64 + lane];
        float m = fmaxf(fmaxf(fabsf(v.x), fabsf(v.y)), fmaxf(fabsf(v.z), fabsf(v.w)));
#pragma unroll
        for (int d = 1; d < 64; d <<= 1) m = fmaxf(m, __shfl_xor(m, d, 64));
        const float inv = (m > 0.f) ? 127.0f / m : 0.f;
        int q0 = (int)rintf(v.x * inv) + 128;
        int q1 = (int)rintf(v.y * inv) + 128;
        int q2 = (int)rintf(v.z * inv) + 128;
        int q3 = (int)rintf(v.w * inv) + 128;
        unsigned int pk = (unsigned int)q0 | ((unsigned int)q1 << 8)
                        | ((unsigned int)q2 << 16) | ((unsigned int)q3 << 24);
        xq[row * 64 + lane] = pk;
        if (lane == 0) scl[row] = m * (1.0f / 127.0f);
    } else {
        const int row = bid - NB_X;        // s*256 + k
        const int s = row >> 8, k = row & 255;
        wt[((size_t)s * OUT_DIM + tid) * D_FEAT + k] = f2bf(W[(size_t)row * OUT_DIM + tid]);
    }
}

// ---------------- passA: LDS-staged binning by dst/80; coalesced burst flush ----------------
// record: .x = src | (bf16(w*scl[src]) << 16)   .y = local bucket lb = s*80 + dst%80
__global__ void __launch_bounds__(256) passA(const int* __restrict__ src, const int* __restrict__ dst,
        const float* __restrict__ w, const float* __restrict__ scl,
        int* __restrict__ gtail, uint2* __restrict__ gbin) {
    __shared__ int lcnt[NBIN];
    __shared__ uint2 lbuf[NBIN][LCAP];     // 60,000 B
    const int tid = threadIdx.x;

    for (int i = tid; i < NBIN; i += 256) lcnt[i] = 0;
    __syncthreads();

    const int e0 = blockIdx.x * PA_BATCH;
#pragma unroll
    for (int k = 0; k < PA_BATCH / 256; ++k) {
        const int e = e0 + k * 256 + tid;
        if (e < TOTAL_E) {
            const int s = e / N_EDGES;
            const int sv = src[e];
            const int dv = dst[e];
            const float wq = w[e] * scl[sv];
            const int bin = dv / BINW;
            uint2 rec;
            rec.x = (unsigned int)sv | (((unsigned int)f2bf(wq)) << 16);
            rec.y = (unsigned int)(s * BINW + (dv - bin * BINW));
            const int pos = atomicAdd(&lcnt[bin], 1);
            if (pos < LCAP) {
                lbuf[bin][pos] = rec;
            } else {                        // rare overflow: direct global append
                const int g = atomicAdd(&gtail[bin], 1);
                if (g < BINCAP) gbin[(size_t)bin * BINCAP + g] = rec;
            }
        }
    }
    __syncthreads();

    // flush: wave wid handles bins wid, wid+4, ...
    const int wid = tid >> 6;
    const int lane = tid & 63;
    for (int bin = wid; bin < NBIN; bin += 4) {
        int n = lcnt[bin]; if (n > LCAP) n = LCAP;
        int base = 0;
        if (lane == 0 && n > 0) base = atomicAdd(&gtail[bin], n);
        base = __shfl(base, 0, 64);
        if (lane < n) {
            const int g = base + lane;
            if (g < BINCAP) gbin[(size_t)bin * BINCAP + g] = lbuf[bin][lane];
        }
    }
}

// ---------------- passB: per-bin bucket placement; LDS atomics; hot epack window ----------------
__global__ void __launch_bounds__(256) passB(const int* __restrict__ gtail,
        const uint2* __restrict__ gbin, int* __restrict__ cursor,
        unsigned int* __restrict__ epack) {
    __shared__ int lcnt2[N_SUPPORT * BINW];    // 240 local buckets
    const int bin = blockIdx.x;
    const int tid = threadIdx.x;

    for (int i = tid; i < N_SUPPORT * BINW; i += 256) lcnt2[i] = 0;
    __syncthreads();

    int m = gtail[bin]; if (m > BINCAP) m = BINCAP;
    const uint2* gb = gbin + (size_t)bin * BINCAP;

    for (int i = tid; i < m; i += 256) {
        const uint2 r = gb[i];
        const int lb = (int)r.y;
        const int pos = atomicAdd(&lcnt2[lb], 1);
        if (pos < CAP) {
            const int s = lb / BINW;
            const int dl = lb - s * BINW;
            const int g = s * N_NODES + bin * BINW + dl;
            epack[(size_t)g * CAP + pos] = r.x;
        }
    }
    __syncthreads();

    // write cursor for every bucket in this bin (covers all 60000 buckets chip-wide)
    for (int lb = tid; lb < N_SUPPORT * BINW; lb += 256) {
        const int s = lb / BINW;
        const int dl = lb - s * BINW;
        const int g = s * N_NODES + bin * BINW + dl;
        int c = lcnt2[lb]; if (c > CAP) c = CAP;
        cursor[g] = c;
    }
}

// ---------------- aggregate: one 32-lane half per (s,node) bucket (unchanged, verified) ----------------
__global__ void __launch_bounds__(256) aggregate(
        const unsigned char* __restrict__ xq, const int* __restrict__ cursor,
        const unsigned int* __restrict__ epack, unsigned short* __restrict__ hb) {
    const int b = blockIdx.x * 8 + (threadIdx.x >> 5);
    const int l32 = threadIdx.x & 31;
    const int xoff = l32 * 8;
    const int s = b / N_NODES;
    const int node = b - s * N_NODES;

    int cnt = cursor[b]; if (cnt > CAP) cnt = CAP;
    const unsigned int* ep = epack + (size_t)b * CAP;

    float a[8];
#pragma unroll
    for (int j = 0; j < 8; ++j) a[j] = 0.f;
    float sw = 0.f;

    int it = 0;
    for (; it + 3 < cnt; it += 4) {
        const uint4 pk = *(const uint4*)(ep + it);
        const uint2 u0 = *(const uint2*)(xq + ((size_t)(pk.x & 0xFFFFu) << 8) + xoff);
        const uint2 u1 = *(const uint2*)(xq + ((size_t)(pk.y & 0xFFFFu) << 8) + xoff);
        const uint2 u2 = *(const uint2*)(xq + ((size_t)(pk.z & 0xFFFFu) << 8) + xoff);
        const uint2 u3 = *(const uint2*)(xq + ((size_t)(pk.w & 0xFFFFu) << 8) + xoff);
        const float w0 = __uint_as_float(pk.x & 0xFFFF0000u);
        const float w1 = __uint_as_float(pk.y & 0xFFFF0000u);
        const float w2 = __uint_as_float(pk.z & 0xFFFF0000u);
        const float w3 = __uint_as_float(pk.w & 0xFFFF0000u);
        sw += w0 + w1 + w2 + w3;
#pragma unroll
        for (int j = 0; j < 4; ++j) {
            const int sh = 8 * j;
            a[j]     += w0 * (float)((u0.x >> sh) & 0xffu) + w1 * (float)((u1.x >> sh) & 0xffu)
                      + w2 * (float)((u2.x >> sh) & 0xffu) + w3 * (float)((u3.x >> sh) & 0xffu);
            a[4 + j] += w0 * (float)((u0.y >> sh) & 0xffu) + w1 * (float)((u1.y >> sh) & 0xffu)
                      + w2 * (float)((u2.y >> sh) & 0xffu) + w3 * (float)((u3.y >> sh) & 0xffu);
        }
    }
    for (; it < cnt; ++it) {
        const unsigned int pe = ep[it];
        const uint2 u = *(const uint2*)(xq + ((size_t)(pe & 0xFFFFu) << 8) + xoff);
        const float wv = __uint_as_float(pe & 0xFFFF0000u);
        sw += wv;
#pragma unroll
        for (int j = 0; j < 4; ++j) {
            const int sh = 8 * j;
            a[j]     += wv * (float)((u.x >> sh) & 0xffu);
            a[4 + j] += wv * (float)((u.y >> sh) & 0xffu);
        }
    }

    ushort8 o;
    const float bias = 128.f * sw;
#pragma unroll
    for (int j = 0; j < 8; ++j) o[j] = f2bf(a[j] - bias);
    *(ushort8*)(hb + (size_t)node * KDIM + s * D_FEAT + xoff) = o;
}

// ---------------- gemm_h: BM=128 tile, LDS-staged B (unchanged, verified) ----------------
__global__ void __launch_bounds__(512) gemm_h(
        const unsigned short* __restrict__ hb, const unsigned short* __restrict__ wt,
        float* __restrict__ out) {
    __shared__ unsigned short bs[OUT_DIM][136];
    const int n0 = blockIdx.x * GM_ROWS;
    const int wid = threadIdx.x >> 6;
    const int lane = threadIdx.x & 63;
    const int cit = lane & 15;
    const int kgrp = (lane >> 4) * 8;
    const bool valid = (n0 + wid * 16) < N_NODES;
    const int arow_idx = valid ? (n0 + wid * 16 + cit) : 0;
    const short* arow = (const short*)hb + (size_t)arow_idx * KDIM + kgrp;

    f32x4 acc[16];
#pragma unroll
    for (int j = 0; j < 16; ++j) acc[j] = (f32x4){0.f, 0.f, 0.f, 0.f};

    for (int kc = 0; kc < 6; ++kc) {
        const int s = kc >> 1;
        const int kb = (kc & 1) * 128;
        if (kc) __syncthreads();
        for (int i = threadIdx.x; i < 4096; i += 512) {
            const int n = i >> 4;
            const int k8 = (i & 15) << 3;
            *(ushort8*)&bs[n][k8] =
                *(const ushort8*)(wt + ((size_t)s * OUT_DIM + n) * D_FEAT + kb + k8);
        }
        __syncthreads();

#pragma unroll
        for (int ks = 0; ks < 4; ++ks) {
            short8 av = *(const short8*)(arow + kc * 128 + ks * 32);
#pragma unroll
            for (int nt = 0; nt < 16; ++nt) {
                short8 bv = *(const short8*)&bs[nt * 16 + cit][ks * 32 + kgrp];
                acc[nt] = __builtin_amdgcn_mfma_f32_16x16x32_bf16(av, bv, acc[nt], 0, 0, 0);
            }
        }
    }

    if (valid) {
        const int rbase = (lane >> 4) * 4;
#pragma unroll
        for (int nt = 0; nt < 16; ++nt) {
            const int col = nt * 16 + cit;
#pragma unroll
            for (int r = 0; r < 4; ++r) {
                out[(size_t)(n0 + wid * 16 + rbase + r) * OUT_DIM + col] = acc[nt][r];
            }
        }
    }
}

extern "C" void kernel_launch(void* const* d_in, const int* in_sizes, int n_in,
                              void* d_out, int out_size, void* d_ws, size_t ws_size,
                              hipStream_t stream) {
    const float* x        = (const float*)d_in[0];
    const int*   edge_src = (const int*)d_in[1];
    const int*   edge_dst = (const int*)d_in[2];
    const float* edge_w   = (const float*)d_in[3];
    const float* W        = (const float*)d_in[4];
    float* out = (float*)d_out;

    char* ws = (char*)d_ws;
    unsigned int*   xq     = (unsigned int*)(ws);                //  5,120,000 B
    float*          scl    = (float*)(ws + 5120000);             //     80,000 B
    unsigned short* wt     = (unsigned short*)(ws + 5200000);    //    393,216 B
    int*            cursor = (int*)(ws + 5593216);               //    240,000 B
    unsigned int*   epack  = (unsigned int*)(ws + 5833216);      // 15,360,000 B
    int*            gtail  = (int*)(ws + 21193216);              //      1,024 B
    uint2*          gbin   = (uint2*)(ws + 21194240);            //  9,216,000 B (250*4608*8)
    unsigned short* hb     = (unsigned short*)(ws + 30410240);   // 30,720,000 B
    // total: 61,130,240 B

    hipMemsetAsync(gtail, 0, 1024, stream);

    prep1<<<NB_X + NB_W, 256, 0, stream>>>(x, W, xq, scl, wt);
    passA<<<PA_BLOCKS, 256, 0, stream>>>(edge_src, edge_dst, edge_w, scl, gtail, gbin);
    passB<<<NBIN, 256, 0, stream>>>(gtail, gbin, cursor, epack);

    aggregate<<<NBUCKET / 8, 256, 0, stream>>>((const unsigned char*)xq, cursor, epack, hb);

    gemm_h<<<GM_BLOCKS, 512, 0, stream>>>(hb, wt, out);
}

// Round 18
// 298.284 us; speedup vs baseline: 1.0605x; 1.0605x over previous
//
#include <hip/hip_runtime.h>

#define N_NODES 20000
#define D_FEAT 256
#define N_SUPPORT 3
#define N_EDGES 320000
#define OUT_DIM 256
#define TOTAL_E (N_SUPPORT * N_EDGES)
#define KDIM (N_SUPPORT * D_FEAT)   // 768
#define NBUCKET (N_SUPPORT * N_NODES)  // 60000
#define GM_ROWS 128
#define GM_BLOCKS ((N_NODES + GM_ROWS - 1) / GM_ROWS)   // 157

typedef __attribute__((ext_vector_type(8))) short short8;
typedef __attribute__((ext_vector_type(8))) unsigned short ushort8;
typedef __attribute__((ext_vector_type(4))) float f32x4;

__device__ inline unsigned short f2bf(float f) {
    unsigned int u = __float_as_uint(f);
    u += 0x7fff + ((u >> 16) & 1);  // round-to-nearest-even
    return (unsigned short)(u >> 16);
}

// ---------------- prep1: quantize_x | convert_w | count (3 independent ranges) ----------------
#define NB_X (N_NODES / 4)          // 5000
#define NB_W (N_SUPPORT * D_FEAT)   // 768
#define NB_C (TOTAL_E / 256)        // 3750

__global__ void __launch_bounds__(256) prep1(const float* __restrict__ x, const float* __restrict__ W,
        const int* __restrict__ dst,
        unsigned int* __restrict__ xq, float* __restrict__ scl, unsigned short* __restrict__ wt,
        int* __restrict__ cnt) {
    const int bid = blockIdx.x;
    const int tid = threadIdx.x;
    if (bid < NB_X) {
        // per-row int8 quantization: row = bid*4 + wid, lane owns 4 cols
        const int row = bid * 4 + (tid >> 6);
        const int lane = tid & 63;
        float4 v = ((const float4*)x)[row * 64 + lane];
        float m = fmaxf(fmaxf(fabsf(v.x), fabsf(v.y)), fmaxf(fabsf(v.z), fabsf(v.w)));
#pragma unroll
        for (int d = 1; d < 64; d <<= 1) m = fmaxf(m, __shfl_xor(m, d, 64));
        const float inv = (m > 0.f) ? 127.0f / m : 0.f;
        int q0 = (int)rintf(v.x * inv) + 128;
        int q1 = (int)rintf(v.y * inv) + 128;
        int q2 = (int)rintf(v.z * inv) + 128;
        int q3 = (int)rintf(v.w * inv) + 128;
        unsigned int pk = (unsigned int)q0 | ((unsigned int)q1 << 8)
                        | ((unsigned int)q2 << 16) | ((unsigned int)q3 << 24);
        xq[row * 64 + lane] = pk;
        if (lane == 0) scl[row] = m * (1.0f / 127.0f);
    } else if (bid < NB_X + NB_W) {
        const int row = bid - NB_X;        // s*256 + k
        const int s = row >> 8, k = row & 255;
        wt[((size_t)s * OUT_DIM + tid) * D_FEAT + k] = f2bf(W[(size_t)row * OUT_DIM + tid]);
    } else {
        const int i = (bid - NB_X - NB_W) * 256 + tid;
        const int s = i / N_EDGES;
        atomicAdd(&cnt[s * N_NODES + dst[i]], 1);
    }
}

// ---------------- scan: 1 block; offsets rounded to 4 records (16B alignment) ----------------
__global__ void __launch_bounds__(256) scan(const int* __restrict__ cnt, int* __restrict__ offsets) {
    __shared__ int partials[256];
    const int tid = threadIdx.x;
    const int CH = (NBUCKET + 255) / 256;   // 235
    const int base = tid * CH;

    int lsum = 0;
    for (int i = 0; i < CH; ++i) {
        int idx = base + i;
        if (idx < NBUCKET) lsum += (cnt[idx] + 3) & ~3;
    }
    partials[tid] = lsum;
    __syncthreads();
    for (int d = 1; d < 256; d <<= 1) {
        int v = (tid >= d) ? partials[tid - d] : 0;
        __syncthreads();
        partials[tid] += v;
        __syncthreads();
    }
    int run = (tid == 0) ? 0 : partials[tid - 1];
    for (int i = 0; i < CH; ++i) {
        int idx = base + i;
        if (idx < NBUCKET) {
            offsets[idx] = run;
            run += (cnt[idx] + 3) & ~3;
        }
    }
}

// ---------------- fill: dense CSR records (compact epack -> L2-resident writes) ----------------
__global__ void __launch_bounds__(256) fill(const int* __restrict__ src, const int* __restrict__ dst,
        const float* __restrict__ w, const float* __restrict__ scl,
        const int* __restrict__ offsets, int* __restrict__ cur,
        unsigned int* __restrict__ epack) {
    const int i = blockIdx.x * 256 + threadIdx.x;
    if (i >= TOTAL_E) return;
    const int s = i / N_EDGES;
    const int sv = src[i];
    const int b = s * N_NODES + dst[i];
    const int pos = atomicAdd(&cur[b], 1);
    const float wq = w[i] * scl[sv];   // fold dequant scale into edge weight
    epack[(size_t)offsets[b] + pos] = (unsigned int)sv | (((unsigned int)f2bf(wq)) << 16);
}

// ---------------- aggregate: one 32-lane half per (s,node) bucket (verified inner loop) ----------------
__global__ void __launch_bounds__(256) aggregate(
        const unsigned char* __restrict__ xq, const int* __restrict__ cnt,
        const int* __restrict__ offsets, const unsigned int* __restrict__ epack,
        unsigned short* __restrict__ hb) {
    const int b = blockIdx.x * 8 + (threadIdx.x >> 5);
    const int l32 = threadIdx.x & 31;
    const int xoff = l32 * 8;
    const int s = b / N_NODES;
    const int node = b - s * N_NODES;

    const int c = cnt[b];
    const unsigned int* ep = epack + (size_t)offsets[b];   // 16B-aligned (offsets %4==0)

    float a[8];
#pragma unroll
    for (int j = 0; j < 8; ++j) a[j] = 0.f;
    float sw = 0.f;

    int it = 0;
    for (; it + 3 < c; it += 4) {        // 4 independent 8B table loads in flight
        const uint4 pk = *(const uint4*)(ep + it);
        const uint2 u0 = *(const uint2*)(xq + ((size_t)(pk.x & 0xFFFFu) << 8) + xoff);
        const uint2 u1 = *(const uint2*)(xq + ((size_t)(pk.y & 0xFFFFu) << 8) + xoff);
        const uint2 u2 = *(const uint2*)(xq + ((size_t)(pk.z & 0xFFFFu) << 8) + xoff);
        const uint2 u3 = *(const uint2*)(xq + ((size_t)(pk.w & 0xFFFFu) << 8) + xoff);
        const float w0 = __uint_as_float(pk.x & 0xFFFF0000u);
        const float w1 = __uint_as_float(pk.y & 0xFFFF0000u);
        const float w2 = __uint_as_float(pk.z & 0xFFFF0000u);
        const float w3 = __uint_as_float(pk.w & 0xFFFF0000u);
        sw += w0 + w1 + w2 + w3;
#pragma unroll
        for (int j = 0; j < 4; ++j) {
            const int sh = 8 * j;
            a[j]     += w0 * (float)((u0.x >> sh) & 0xffu) + w1 * (float)((u1.x >> sh) & 0xffu)
                      + w2 * (float)((u2.x >> sh) & 0xffu) + w3 * (float)((u3.x >> sh) & 0xffu);
            a[4 + j] += w0 * (float)((u0.y >> sh) & 0xffu) + w1 * (float)((u1.y >> sh) & 0xffu)
                      + w2 * (float)((u2.y >> sh) & 0xffu) + w3 * (float)((u3.y >> sh) & 0xffu);
        }
    }
    for (; it < c; ++it) {               // <=3 cleanup iterations
        const unsigned int pe = ep[it];
        const uint2 u = *(const uint2*)(xq + ((size_t)(pe & 0xFFFFu) << 8) + xoff);
        const float wv = __uint_as_float(pe & 0xFFFF0000u);
        sw += wv;
#pragma unroll
        for (int j = 0; j < 4; ++j) {
            const int sh = 8 * j;
            a[j]     += wv * (float)((u.x >> sh) & 0xffu);
            a[4 + j] += wv * (float)((u.y >> sh) & 0xffu);
        }
    }

    ushort8 o;
    const float bias = 128.f * sw;
#pragma unroll
    for (int j = 0; j < 8; ++j) o[j] = f2bf(a[j] - bias);
    *(ushort8*)(hb + (size_t)node * KDIM + s * D_FEAT + xoff) = o;
}

// ---------------- gemm_h: BM=128 tile, LDS-staged B (unchanged, verified) ----------------
__global__ void __launch_bounds__(512) gemm_h(
        const unsigned short* __restrict__ hb, const unsigned short* __restrict__ wt,
        float* __restrict__ out) {
    __shared__ unsigned short bs[OUT_DIM][136];
    const int n0 = blockIdx.x * GM_ROWS;
    const int wid = threadIdx.x >> 6;
    const int lane = threadIdx.x & 63;
    const int cit = lane & 15;
    const int kgrp = (lane >> 4) * 8;
    const bool valid = (n0 + wid * 16) < N_NODES;
    const int arow_idx = valid ? (n0 + wid * 16 + cit) : 0;
    const short* arow = (const short*)hb + (size_t)arow_idx * KDIM + kgrp;

    f32x4 acc[16];
#pragma unroll
    for (int j = 0; j < 16; ++j) acc[j] = (f32x4){0.f, 0.f, 0.f, 0.f};

    for (int kc = 0; kc < 6; ++kc) {
        const int s = kc >> 1;
        const int kb = (kc & 1) * 128;
        if (kc) __syncthreads();
        for (int i = threadIdx.x; i < 4096; i += 512) {
            const int n = i >> 4;
            const int k8 = (i & 15) << 3;
            *(ushort8*)&bs[n][k8] =
                *(const ushort8*)(wt + ((size_t)s * OUT_DIM + n) * D_FEAT + kb + k8);
        }
        __syncthreads();

#pragma unroll
        for (int ks = 0; ks < 4; ++ks) {
            short8 av = *(const short8*)(arow + kc * 128 + ks * 32);
#pragma unroll
            for (int nt = 0; nt < 16; ++nt) {
                short8 bv = *(const short8*)&bs[nt * 16 + cit][ks * 32 + kgrp];
                acc[nt] = __builtin_amdgcn_mfma_f32_16x16x32_bf16(av, bv, acc[nt], 0, 0, 0);
            }
        }
    }

    if (valid) {
        const int rbase = (lane >> 4) * 4;
#pragma unroll
        for (int nt = 0; nt < 16; ++nt) {
            const int col = nt * 16 + cit;
#pragma unroll
            for (int r = 0; r < 4; ++r) {
                out[(size_t)(n0 + wid * 16 + rbase + r) * OUT_DIM + col] = acc[nt][r];
            }
        }
    }
}

extern "C" void kernel_launch(void* const* d_in, const int* in_sizes, int n_in,
                              void* d_out, int out_size, void* d_ws, size_t ws_size,
                              hipStream_t stream) {
    const float* x        = (const float*)d_in[0];
    const int*   edge_src = (const int*)d_in[1];
    const int*   edge_dst = (const int*)d_in[2];
    const float* edge_w   = (const float*)d_in[3];
    const float* W        = (const float*)d_in[4];
    float* out = (float*)d_out;

    char* ws = (char*)d_ws;
    unsigned int*   xq      = (unsigned int*)(ws);               //  5,120,000 B
    float*          scl     = (float*)(ws + 5120000);            //     80,000 B
    unsigned short* wt      = (unsigned short*)(ws + 5200000);   //    393,216 B
    int*            cnt     = (int*)(ws + 5593216);              //    240,000 B
    int*            cur     = (int*)(ws + 5833216);              //    240,000 B
    int*            offsets = (int*)(ws + 6073216);              //    240,064 B
    unsigned int*   epack   = (unsigned int*)(ws + 6313280);     //  4,608,000 B (dense CSR, padded to 4)
    unsigned short* hb      = (unsigned short*)(ws + 10921280);  // 30,720,000 B
    // total: 41,641,280 B

    hipMemsetAsync(cnt, 0, 480000, stream);   // cnt + cur (contiguous)

    prep1<<<NB_X + NB_W + NB_C, 256, 0, stream>>>(x, W, edge_dst, xq, scl, wt, cnt);
    scan<<<1, 256, 0, stream>>>(cnt, offsets);
    fill<<<NB_C, 256, 0, stream>>>(edge_src, edge_dst, edge_w, scl, offsets, cur, epack);

    aggregate<<<NBUCKET / 8, 256, 0, stream>>>((const unsigned char*)xq, cnt, offsets, epack, hb);

    gemm_h<<<GM_BLOCKS, 512, 0, stream>>>(hb, wt, out);
}

// Round 19
// 178.081 us; speedup vs baseline: 1.7763x; 1.6750x over previous
//
#include <hip/hip_runtime.h>

#define N_NODES 20000
#define D_FEAT 256
#define N_SUPPORT 3
#define N_EDGES 320000
#define OUT_DIM 256
#define TOTAL_E (N_SUPPORT * N_EDGES)
#define KDIM (N_SUPPORT * D_FEAT)   // 768
#define NBUCKET (N_SUPPORT * N_NODES)  // 60000
#define GM_ROWS 128
#define GM_BLOCKS ((N_NODES + GM_ROWS - 1) / GM_ROWS)   // 157

typedef __attribute__((ext_vector_type(8))) short short8;
typedef __attribute__((ext_vector_type(8))) unsigned short ushort8;
typedef __attribute__((ext_vector_type(4))) float f32x4;

__device__ inline unsigned short f2bf(float f) {
    unsigned int u = __float_as_uint(f);
    u += 0x7fff + ((u >> 16) & 1);  // round-to-nearest-even
    return (unsigned short)(u >> 16);
}

// ---------------- prep1: quantize_x | convert_w | count (3 independent ranges) ----------------
#define NB_X (N_NODES / 4)          // 5000
#define NB_W (N_SUPPORT * D_FEAT)   // 768
#define NB_C (TOTAL_E / 256)        // 3750

__global__ void __launch_bounds__(256) prep1(const float* __restrict__ x, const float* __restrict__ W,
        const int* __restrict__ dst,
        unsigned int* __restrict__ xq, float* __restrict__ scl, unsigned short* __restrict__ wt,
        int* __restrict__ cnt) {
    const int bid = blockIdx.x;
    const int tid = threadIdx.x;
    if (bid < NB_X) {
        // per-row int8 quantization: row = bid*4 + wid, lane owns 4 cols
        const int row = bid * 4 + (tid >> 6);
        const int lane = tid & 63;
        float4 v = ((const float4*)x)[row * 64 + lane];
        float m = fmaxf(fmaxf(fabsf(v.x), fabsf(v.y)), fmaxf(fabsf(v.z), fabsf(v.w)));
#pragma unroll
        for (int d = 1; d < 64; d <<= 1) m = fmaxf(m, __shfl_xor(m, d, 64));
        const float inv = (m > 0.f) ? 127.0f / m : 0.f;
        int q0 = (int)rintf(v.x * inv) + 128;
        int q1 = (int)rintf(v.y * inv) + 128;
        int q2 = (int)rintf(v.z * inv) + 128;
        int q3 = (int)rintf(v.w * inv) + 128;
        unsigned int pk = (unsigned int)q0 | ((unsigned int)q1 << 8)
                        | ((unsigned int)q2 << 16) | ((unsigned int)q3 << 24);
        xq[row * 64 + lane] = pk;
        if (lane == 0) scl[row] = m * (1.0f / 127.0f);
    } else if (bid < NB_X + NB_W) {
        const int row = bid - NB_X;        // s*256 + k
        const int s = row >> 8, k = row & 255;
        wt[((size_t)s * OUT_DIM + tid) * D_FEAT + k] = f2bf(W[(size_t)row * OUT_DIM + tid]);
    } else {
        const int i = (bid - NB_X - NB_W) * 256 + tid;
        const int s = i / N_EDGES;
        atomicAdd(&cnt[s * N_NODES + dst[i]], 1);
    }
}

// ---------------- scan_alloc: parallel disjoint-range allocation (order-free CSR) ----------------
// Each wave: in-wave exclusive prefix of padded counts, one atomicAdd on tail per wave.
// aggregate only needs disjoint 16B-aligned ranges -> allocation order irrelevant.
__global__ void __launch_bounds__(256) scan_alloc(const int* __restrict__ cnt,
        int* __restrict__ offsets, int* __restrict__ tail) {
    const int b = blockIdx.x * 256 + threadIdx.x;
    const int lane = threadIdx.x & 63;
    int padded = 0;
    if (b < NBUCKET) padded = (cnt[b] + 3) & ~3;

    // inclusive prefix within wave
    int incl = padded;
#pragma unroll
    for (int d = 1; d < 64; d <<= 1) {
        int v = __shfl_up(incl, d, 64);
        if (lane >= d) incl += v;
    }
    const int excl = incl - padded;
    const int wave_total = __shfl(incl, 63, 64);

    int base = 0;
    if (lane == 0 && wave_total > 0) base = atomicAdd(tail, wave_total);
    base = __shfl(base, 0, 64);

    if (b < NBUCKET) offsets[b] = base + excl;
}

// ---------------- fill: dense CSR records (compact epack -> L2-resident writes) ----------------
__global__ void __launch_bounds__(256) fill(const int* __restrict__ src, const int* __restrict__ dst,
        const float* __restrict__ w, const float* __restrict__ scl,
        const int* __restrict__ offsets, int* __restrict__ cur,
        unsigned int* __restrict__ epack) {
    const int i = blockIdx.x * 256 + threadIdx.x;
    if (i >= TOTAL_E) return;
    const int s = i / N_EDGES;
    const int sv = src[i];
    const int b = s * N_NODES + dst[i];
    const int pos = atomicAdd(&cur[b], 1);
    const float wq = w[i] * scl[sv];   // fold dequant scale into edge weight
    epack[(size_t)offsets[b] + pos] = (unsigned int)sv | (((unsigned int)f2bf(wq)) << 16);
}

// ---------------- aggregate: one 32-lane half per (s,node) bucket (verified inner loop) ----------------
__global__ void __launch_bounds__(256) aggregate(
        const unsigned char* __restrict__ xq, const int* __restrict__ cnt,
        const int* __restrict__ offsets, const unsigned int* __restrict__ epack,
        unsigned short* __restrict__ hb) {
    const int b = blockIdx.x * 8 + (threadIdx.x >> 5);
    const int l32 = threadIdx.x & 31;
    const int xoff = l32 * 8;
    const int s = b / N_NODES;
    const int node = b - s * N_NODES;

    const int c = cnt[b];
    const unsigned int* ep = epack + (size_t)offsets[b];   // 16B-aligned (padded %4==0)

    float a[8];
#pragma unroll
    for (int j = 0; j < 8; ++j) a[j] = 0.f;
    float sw = 0.f;

    int it = 0;
    for (; it + 3 < c; it += 4) {        // 4 independent 8B table loads in flight
        const uint4 pk = *(const uint4*)(ep + it);
        const uint2 u0 = *(const uint2*)(xq + ((size_t)(pk.x & 0xFFFFu) << 8) + xoff);
        const uint2 u1 = *(const uint2*)(xq + ((size_t)(pk.y & 0xFFFFu) << 8) + xoff);
        const uint2 u2 = *(const uint2*)(xq + ((size_t)(pk.z & 0xFFFFu) << 8) + xoff);
        const uint2 u3 = *(const uint2*)(xq + ((size_t)(pk.w & 0xFFFFu) << 8) + xoff);
        const float w0 = __uint_as_float(pk.x & 0xFFFF0000u);
        const float w1 = __uint_as_float(pk.y & 0xFFFF0000u);
        const float w2 = __uint_as_float(pk.z & 0xFFFF0000u);
        const float w3 = __uint_as_float(pk.w & 0xFFFF0000u);
        sw += w0 + w1 + w2 + w3;
#pragma unroll
        for (int j = 0; j < 4; ++j) {
            const int sh = 8 * j;
            a[j]     += w0 * (float)((u0.x >> sh) & 0xffu) + w1 * (float)((u1.x >> sh) & 0xffu)
                      + w2 * (float)((u2.x >> sh) & 0xffu) + w3 * (float)((u3.x >> sh) & 0xffu);
            a[4 + j] += w0 * (float)((u0.y >> sh) & 0xffu) + w1 * (float)((u1.y >> sh) & 0xffu)
                      + w2 * (float)((u2.y >> sh) & 0xffu) + w3 * (float)((u3.y >> sh) & 0xffu);
        }
    }
    for (; it < c; ++it) {               // <=3 cleanup iterations
        const unsigned int pe = ep[it];
        const uint2 u = *(const uint2*)(xq + ((size_t)(pe & 0xFFFFu) << 8) + xoff);
        const float wv = __uint_as_float(pe & 0xFFFF0000u);
        sw += wv;
#pragma unroll
        for (int j = 0; j < 4; ++j) {
            const int sh = 8 * j;
            a[j]     += wv * (float)((u.x >> sh) & 0xffu);
            a[4 + j] += wv * (float)((u.y >> sh) & 0xffu);
        }
    }

    ushort8 o;
    const float bias = 128.f * sw;
#pragma unroll
    for (int j = 0; j < 8; ++j) o[j] = f2bf(a[j] - bias);
    *(ushort8*)(hb + (size_t)node * KDIM + s * D_FEAT + xoff) = o;
}

// ---------------- gemm_h: BM=128 tile, LDS-staged B (unchanged, verified) ----------------
__global__ void __launch_bounds__(512) gemm_h(
        const unsigned short* __restrict__ hb, const unsigned short* __restrict__ wt,
        float* __restrict__ out) {
    __shared__ unsigned short bs[OUT_DIM][136];
    const int n0 = blockIdx.x * GM_ROWS;
    const int wid = threadIdx.x >> 6;
    const int lane = threadIdx.x & 63;
    const int cit = lane & 15;
    const int kgrp = (lane >> 4) * 8;
    const bool valid = (n0 + wid * 16) < N_NODES;
    const int arow_idx = valid ? (n0 + wid * 16 + cit) : 0;
    const short* arow = (const short*)hb + (size_t)arow_idx * KDIM + kgrp;

    f32x4 acc[16];
#pragma unroll
    for (int j = 0; j < 16; ++j) acc[j] = (f32x4){0.f, 0.f, 0.f, 0.f};

    for (int kc = 0; kc < 6; ++kc) {
        const int s = kc >> 1;
        const int kb = (kc & 1) * 128;
        if (kc) __syncthreads();
        for (int i = threadIdx.x; i < 4096; i += 512) {
            const int n = i >> 4;
            const int k8 = (i & 15) << 3;
            *(ushort8*)&bs[n][k8] =
                *(const ushort8*)(wt + ((size_t)s * OUT_DIM + n) * D_FEAT + kb + k8);
        }
        __syncthreads();

#pragma unroll
        for (int ks = 0; ks < 4; ++ks) {
            short8 av = *(const short8*)(arow + kc * 128 + ks * 32);
#pragma unroll
            for (int nt = 0; nt < 16; ++nt) {
                short8 bv = *(const short8*)&bs[nt * 16 + cit][ks * 32 + kgrp];
                acc[nt] = __builtin_amdgcn_mfma_f32_16x16x32_bf16(av, bv, acc[nt], 0, 0, 0);
            }
        }
    }

    if (valid) {
        const int rbase = (lane >> 4) * 4;
#pragma unroll
        for (int nt = 0; nt < 16; ++nt) {
            const int col = nt * 16 + cit;
#pragma unroll
            for (int r = 0; r < 4; ++r) {
                out[(size_t)(n0 + wid * 16 + rbase + r) * OUT_DIM + col] = acc[nt][r];
            }
        }
    }
}

extern "C" void kernel_launch(void* const* d_in, const int* in_sizes, int n_in,
                              void* d_out, int out_size, void* d_ws, size_t ws_size,
                              hipStream_t stream) {
    const float* x        = (const float*)d_in[0];
    const int*   edge_src = (const int*)d_in[1];
    const int*   edge_dst = (const int*)d_in[2];
    const float* edge_w   = (const float*)d_in[3];
    const float* W        = (const float*)d_in[4];
    float* out = (float*)d_out;

    char* ws = (char*)d_ws;
    unsigned int*   xq      = (unsigned int*)(ws);               //  5,120,000 B
    float*          scl     = (float*)(ws + 5120000);            //     80,000 B
    unsigned short* wt      = (unsigned short*)(ws + 5200000);   //    393,216 B
    int*            cnt     = (int*)(ws + 5593216);              //    240,000 B
    int*            cur     = (int*)(ws + 5833216);              //    240,000 B
    int*            tail    = (int*)(ws + 6073216);              //         64 B
    int*            offsets = (int*)(ws + 6073280);              //    240,000 B
    unsigned int*   epack   = (unsigned int*)(ws + 6313280);     //  4,608,000 B (dense CSR, padded to 4)
    unsigned short* hb      = (unsigned short*)(ws + 10921280);  // 30,720,000 B
    // total: 41,641,280 B

    hipMemsetAsync(cnt, 0, 480064, stream);   // cnt + cur + tail (contiguous)

    prep1<<<NB_X + NB_W + NB_C, 256, 0, stream>>>(x, W, edge_dst, xq, scl, wt, cnt);
    scan_alloc<<<(NBUCKET + 255) / 256, 256, 0, stream>>>(cnt, offsets, tail);
    fill<<<NB_C, 256, 0, stream>>>(edge_src, edge_dst, edge_w, scl, offsets, cur, epack);

    aggregate<<<NBUCKET / 8, 256, 0, stream>>>((const unsigned char*)xq, cnt, offsets, epack, hb);

    gemm_h<<<GM_BLOCKS, 512, 0, stream>>>(hb, wt, out);
}

// Round 20
// 146.462 us; speedup vs baseline: 2.1598x; 1.2159x over previous
//
#include <hip/hip_runtime.h>

#define N_NODES 20000
#define D_FEAT 256
#define N_SUPPORT 3
#define N_EDGES 320000
#define OUT_DIM 256
#define TOTAL_E (N_SUPPORT * N_EDGES)
#define CAP 64                      // per-(s,dst) bucket; mean 16, P(>64) ~ 1e-9
#define KDIM (N_SUPPORT * D_FEAT)   // 768
#define NBUCKET (N_SUPPORT * N_NODES)  // 60000
#define GM_ROWS 128
#define GM_BLOCKS ((N_NODES + GM_ROWS - 1) / GM_ROWS)   // 157

typedef __attribute__((ext_vector_type(8))) short short8;
typedef __attribute__((ext_vector_type(8))) unsigned short ushort8;
typedef __attribute__((ext_vector_type(4))) float f32x4;

__device__ inline unsigned short f2bf(float f) {
    unsigned int u = __float_as_uint(f);
    u += 0x7fff + ((u >> 16) & 1);  // round-to-nearest-even
    return (unsigned short)(u >> 16);
}

// ---------------- prep: quantize_x | convert_w | fill_raw (3 INDEPENDENT ranges) ----------------
// fill stores RAW bf16 weight (no scl read -> no cross-range race, r12 lesson);
// aggregate applies scl[sv] at use. Ranges overlap across CUs: fill's scatter-write
// phase hides under quant's read-bound work.
#define NB_X (N_NODES / 4)          // 5000
#define NB_W (N_SUPPORT * D_FEAT)   // 768
#define NB_F (TOTAL_E / 256)        // 3750

__global__ void __launch_bounds__(256) prep(const float* __restrict__ x, const float* __restrict__ W,
        const int* __restrict__ src, const int* __restrict__ dst, const float* __restrict__ w,
        unsigned int* __restrict__ xq, float* __restrict__ scl, unsigned short* __restrict__ wt,
        int* __restrict__ cur, unsigned int* __restrict__ epack) {
    const int bid = blockIdx.x;
    const int tid = threadIdx.x;
    if (bid < NB_X) {
        // per-row int8 quantization: row = bid*4 + wid, lane owns 4 cols
        const int row = bid * 4 + (tid >> 6);
        const int lane = tid & 63;
        float4 v = ((const float4*)x)[row * 64 + lane];
        float m = fmaxf(fmaxf(fabsf(v.x), fabsf(v.y)), fmaxf(fabsf(v.z), fabsf(v.w)));
#pragma unroll
        for (int d = 1; d < 64; d <<= 1) m = fmaxf(m, __shfl_xor(m, d, 64));
        const float inv = (m > 0.f) ? 127.0f / m : 0.f;
        int q0 = (int)rintf(v.x * inv) + 128;
        int q1 = (int)rintf(v.y * inv) + 128;
        int q2 = (int)rintf(v.z * inv) + 128;
        int q3 = (int)rintf(v.w * inv) + 128;
        unsigned int pk = (unsigned int)q0 | ((unsigned int)q1 << 8)
                        | ((unsigned int)q2 << 16) | ((unsigned int)q3 << 24);
        xq[row * 64 + lane] = pk;
        if (lane == 0) scl[row] = m * (1.0f / 127.0f);
    } else if (bid < NB_X + NB_W) {
        const int row = bid - NB_X;        // s*256 + k
        const int s = row >> 8, k = row & 255;
        wt[((size_t)s * OUT_DIM + tid) * D_FEAT + k] = f2bf(W[(size_t)row * OUT_DIM + tid]);
    } else {
        const int i = (bid - NB_X - NB_W) * 256 + tid;
        const int s = i / N_EDGES;
        const int b = s * N_NODES + dst[i];
        const int pos = atomicAdd(&cur[b], 1);
        if (pos < CAP)
            epack[(size_t)b * CAP + pos] = (unsigned int)src[i] | (((unsigned int)f2bf(w[i])) << 16);
    }
}

// ---------------- aggregate: one 32-lane half per (s,node) bucket; scl applied at use ----------------
__global__ void __launch_bounds__(256) aggregate(
        const unsigned char* __restrict__ xq, const float* __restrict__ scl,
        const int* __restrict__ cur, const unsigned int* __restrict__ epack,
        unsigned short* __restrict__ hb) {
    const int b = blockIdx.x * 8 + (threadIdx.x >> 5);
    const int l32 = threadIdx.x & 31;
    const int xoff = l32 * 8;
    const int s = b / N_NODES;
    const int node = b - s * N_NODES;

    int c = cur[b]; if (c > CAP) c = CAP;
    const unsigned int* ep = epack + (size_t)b * CAP;

    float a[8];
#pragma unroll
    for (int j = 0; j < 8; ++j) a[j] = 0.f;
    float sw = 0.f;

    int it = 0;
    for (; it + 3 < c; it += 4) {        // 4 independent 8B table loads in flight
        const uint4 pk = *(const uint4*)(ep + it);
        const unsigned int s0 = pk.x & 0xFFFFu, s1 = pk.y & 0xFFFFu;
        const unsigned int s2 = pk.z & 0xFFFFu, s3 = pk.w & 0xFFFFu;
        const uint2 u0 = *(const uint2*)(xq + ((size_t)s0 << 8) + xoff);
        const uint2 u1 = *(const uint2*)(xq + ((size_t)s1 << 8) + xoff);
        const uint2 u2 = *(const uint2*)(xq + ((size_t)s2 << 8) + xoff);
        const uint2 u3 = *(const uint2*)(xq + ((size_t)s3 << 8) + xoff);
        const float w0 = __uint_as_float(pk.x & 0xFFFF0000u) * scl[s0];
        const float w1 = __uint_as_float(pk.y & 0xFFFF0000u) * scl[s1];
        const float w2 = __uint_as_float(pk.z & 0xFFFF0000u) * scl[s2];
        const float w3 = __uint_as_float(pk.w & 0xFFFF0000u) * scl[s3];
        sw += w0 + w1 + w2 + w3;
#pragma unroll
        for (int j = 0; j < 4; ++j) {
            const int sh = 8 * j;
            a[j]     += w0 * (float)((u0.x >> sh) & 0xffu) + w1 * (float)((u1.x >> sh) & 0xffu)
                      + w2 * (float)((u2.x >> sh) & 0xffu) + w3 * (float)((u3.x >> sh) & 0xffu);
            a[4 + j] += w0 * (float)((u0.y >> sh) & 0xffu) + w1 * (float)((u1.y >> sh) & 0xffu)
                      + w2 * (float)((u2.y >> sh) & 0xffu) + w3 * (float)((u3.y >> sh) & 0xffu);
        }
    }
    for (; it < c; ++it) {               // <=3 cleanup iterations
        const unsigned int pe = ep[it];
        const unsigned int sv = pe & 0xFFFFu;
        const uint2 u = *(const uint2*)(xq + ((size_t)sv << 8) + xoff);
        const float wv = __uint_as_float(pe & 0xFFFF0000u) * scl[sv];
        sw += wv;
#pragma unroll
        for (int j = 0; j < 4; ++j) {
            const int sh = 8 * j;
            a[j]     += wv * (float)((u.x >> sh) & 0xffu);
            a[4 + j] += wv * (float)((u.y >> sh) & 0xffu);
        }
    }

    ushort8 o;
    const float bias = 128.f * sw;
#pragma unroll
    for (int j = 0; j < 8; ++j) o[j] = f2bf(a[j] - bias);
    *(ushort8*)(hb + (size_t)node * KDIM + s * D_FEAT + xoff) = o;
}

// ---------------- gemm_h: BM=128 tile, LDS-staged B (unchanged, verified) ----------------
__global__ void __launch_bounds__(512) gemm_h(
        const unsigned short* __restrict__ hb, const unsigned short* __restrict__ wt,
        float* __restrict__ out) {
    __shared__ unsigned short bs[OUT_DIM][136];
    const int n0 = blockIdx.x * GM_ROWS;
    const int wid = threadIdx.x >> 6;
    const int lane = threadIdx.x & 63;
    const int cit = lane & 15;
    const int kgrp = (lane >> 4) * 8;
    const bool valid = (n0 + wid * 16) < N_NODES;
    const int arow_idx = valid ? (n0 + wid * 16 + cit) : 0;
    const short* arow = (const short*)hb + (size_t)arow_idx * KDIM + kgrp;

    f32x4 acc[16];
#pragma unroll
    for (int j = 0; j < 16; ++j) acc[j] = (f32x4){0.f, 0.f, 0.f, 0.f};

    for (int kc = 0; kc < 6; ++kc) {
        const int s = kc >> 1;
        const int kb = (kc & 1) * 128;
        if (kc) __syncthreads();
        for (int i = threadIdx.x; i < 4096; i += 512) {
            const int n = i >> 4;
            const int k8 = (i & 15) << 3;
            *(ushort8*)&bs[n][k8] =
                *(const ushort8*)(wt + ((size_t)s * OUT_DIM + n) * D_FEAT + kb + k8);
        }
        __syncthreads();

#pragma unroll
        for (int ks = 0; ks < 4; ++ks) {
            short8 av = *(const short8*)(arow + kc * 128 + ks * 32);
#pragma unroll
            for (int nt = 0; nt < 16; ++nt) {
                short8 bv = *(const short8*)&bs[nt * 16 + cit][ks * 32 + kgrp];
                acc[nt] = __builtin_amdgcn_mfma_f32_16x16x32_bf16(av, bv, acc[nt], 0, 0, 0);
            }
        }
    }

    if (valid) {
        const int rbase = (lane >> 4) * 4;
#pragma unroll
        for (int nt = 0; nt < 16; ++nt) {
            const int col = nt * 16 + cit;
#pragma unroll
            for (int r = 0; r < 4; ++r) {
                out[(size_t)(n0 + wid * 16 + rbase + r) * OUT_DIM + col] = acc[nt][r];
            }
        }
    }
}

extern "C" void kernel_launch(void* const* d_in, const int* in_sizes, int n_in,
                              void* d_out, int out_size, void* d_ws, size_t ws_size,
                              hipStream_t stream) {
    const float* x        = (const float*)d_in[0];
    const int*   edge_src = (const int*)d_in[1];
    const int*   edge_dst = (const int*)d_in[2];
    const float* edge_w   = (const float*)d_in[3];
    const float* W        = (const float*)d_in[4];
    float* out = (float*)d_out;

    char* ws = (char*)d_ws;
    unsigned int*   xq     = (unsigned int*)(ws);                //  5,120,000 B (int8 table)
    float*          scl    = (float*)(ws + 5120000);             //     80,000 B
    unsigned short* wt     = (unsigned short*)(ws + 5200000);    //    393,216 B
    int*            cur    = (int*)(ws + 5593216);               //    240,000 B
    unsigned int*   epack  = (unsigned int*)(ws + 5833216);      // 15,360,000 B (CAP-padded)
    unsigned short* hb     = (unsigned short*)(ws + 21193216);   // 30,720,000 B
    // total: 51,913,216 B

    hipMemsetAsync(cur, 0, 240000, stream);

    prep<<<NB_X + NB_W + NB_F, 256, 0, stream>>>(x, W, edge_src, edge_dst, edge_w,
                                                 xq, scl, wt, cur, epack);

    aggregate<<<NBUCKET / 8, 256, 0, stream>>>((const unsigned char*)xq, scl, cur, epack, hb);

    gemm_h<<<GM_BLOCKS, 512, 0, stream>>>(hb, wt, out);
}

// Round 21
// 129.784 us; speedup vs baseline: 2.4374x; 1.1285x over previous
//
#include <hip/hip_runtime.h>

#define N_NODES 20000
#define D_FEAT 256
#define N_SUPPORT 3
#define N_EDGES 320000
#define OUT_DIM 256
#define TOTAL_E (N_SUPPORT * N_EDGES)
#define CAP 64                      // compacted per-bucket capacity
#define CAPX 16                     // per-(bucket,window) capacity; lambda=2 exact
#define NWIN 8
#define KDIM (N_SUPPORT * D_FEAT)   // 768
#define NBUCKET (N_SUPPORT * N_NODES)  // 60000
#define GM_ROWS 128
#define GM_BLOCKS ((N_NODES + GM_ROWS - 1) / GM_ROWS)   // 157

typedef __attribute__((ext_vector_type(8))) short short8;
typedef __attribute__((ext_vector_type(8))) unsigned short ushort8;
typedef __attribute__((ext_vector_type(4))) float f32x4;

__device__ inline unsigned short f2bf(float f) {
    unsigned int u = __float_as_uint(f);
    u += 0x7fff + ((u >> 16) & 1);  // round-to-nearest-even
    return (unsigned short)(u >> 16);
}

// ---------------- prep1: quantize_x (4 rows/wave, ILP-4) | convert_w ----------------
#define NB_X (N_NODES / 16)         // 1250 blocks, 4 waves, 4 rows/wave
#define NB_W (N_SUPPORT * D_FEAT)   // 768
#define NB_F (TOTAL_E / 256)        // 3750

__global__ void __launch_bounds__(256) prep1(const float* __restrict__ x, const float* __restrict__ W,
        unsigned int* __restrict__ xq, float* __restrict__ scl, unsigned short* __restrict__ wt) {
    const int bid = blockIdx.x;
    const int tid = threadIdx.x;
    if (bid < NB_X) {
        const int wid = tid >> 6;
        const int lane = tid & 63;
        const int row0 = bid * 16 + wid * 4;
        float4 v[4];
        float m[4];
#pragma unroll
        for (int r = 0; r < 4; ++r) {
            v[r] = ((const float4*)x)[(size_t)(row0 + r) * 64 + lane];
            m[r] = fmaxf(fmaxf(fabsf(v[r].x), fabsf(v[r].y)), fmaxf(fabsf(v[r].z), fabsf(v[r].w)));
        }
#pragma unroll
        for (int d = 1; d < 64; d <<= 1) {
#pragma unroll
            for (int r = 0; r < 4; ++r) m[r] = fmaxf(m[r], __shfl_xor(m[r], d, 64));
        }
#pragma unroll
        for (int r = 0; r < 4; ++r) {
            const float inv = (m[r] > 0.f) ? 127.0f / m[r] : 0.f;
            int q0 = (int)rintf(v[r].x * inv) + 128;
            int q1 = (int)rintf(v[r].y * inv) + 128;
            int q2 = (int)rintf(v[r].z * inv) + 128;
            int q3 = (int)rintf(v[r].w * inv) + 128;
            unsigned int pk = (unsigned int)q0 | ((unsigned int)q1 << 8)
                            | ((unsigned int)q2 << 16) | ((unsigned int)q3 << 24);
            xq[(size_t)(row0 + r) * 64 + lane] = pk;
            if (lane == 0) scl[row0 + r] = m[r] * (1.0f / 127.0f);
        }
    } else {
        const int row = bid - NB_X;        // s*256 + k
        const int s = row >> 8, k = row & 255;
        wt[((size_t)s * OUT_DIM + tid) * D_FEAT + k] = f2bf(W[(size_t)row * OUT_DIM + tid]);
    }
}

// ---------------- fill_win: scatter into per-window (XCD-local) sub-buckets ----------------
// window = blockIdx.x & 7: under round-robin dispatch each window is written by ONE
// XCD -> its 3.84 MB window + cursor slice stay L2-resident until kernel-end flush.
// Sub-bucket = one 64B line (16 records x 4B). lambda = 2 exact (deterministic
// edge partition), P(>16) ~ 1e-11.
__global__ void __launch_bounds__(256) fill_win(const int* __restrict__ src,
        const int* __restrict__ dst, const float* __restrict__ w, const float* __restrict__ scl,
        int* __restrict__ cur8, unsigned int* __restrict__ ep1) {
    const int i = blockIdx.x * 256 + threadIdx.x;
    if (i >= TOTAL_E) return;
    const int win = blockIdx.x & (NWIN - 1);
    const int s = i / N_EDGES;
    const int sv = src[i];
    const int b = s * N_NODES + dst[i];
    const int pos = atomicAdd(&cur8[win * NBUCKET + b], 1);
    if (pos < CAPX) {
        const float wq = w[i] * scl[sv];
        ep1[((size_t)win * NBUCKET + b) * CAPX + pos] =
            (unsigned int)sv | (((unsigned int)f2bf(wq)) << 16);
    }
}

// ---------------- compact: merge 8 sub-buckets -> contiguous CAP=64 records ----------------
// Half-wave (32 lanes) per bucket; 8 buckets per 256-thr block.
__global__ void __launch_bounds__(256) compact(const int* __restrict__ cur8,
        const unsigned int* __restrict__ ep1, int* __restrict__ cnt2,
        unsigned int* __restrict__ ep2) {
    const int b = blockIdx.x * 8 + (threadIdx.x >> 5);
    const int l32 = threadIdx.x & 31;

    int myc = 0;
    if (l32 < NWIN) {
        int c = cur8[l32 * NBUCKET + b];
        myc = (c > CAPX) ? CAPX : c;
    }
    int cx[NWIN], off[NWIN];
    int tot = 0;
#pragma unroll
    for (int xw = 0; xw < NWIN; ++xw) {
        cx[xw] = __shfl(myc, xw, 32);   // width 32: stay within the half-wave
        off[xw] = tot;
        tot += cx[xw];
    }
    if (tot > CAP) tot = CAP;

    for (int i = l32; i < tot; i += 32) {
        int xw = 0, idx = 0;
#pragma unroll
        for (int t = 0; t < NWIN; ++t) {
            if (i >= off[t] && i < off[t] + cx[t]) { xw = t; idx = i - off[t]; }
        }
        ep2[(size_t)b * CAP + i] = ep1[((size_t)xw * NBUCKET + b) * CAPX + idx];
    }
    if (l32 == 0) cnt2[b] = tot;
}

// ---------------- aggregate: one 32-lane half per bucket (r16-verified body) ----------------
__global__ void __launch_bounds__(256) aggregate(
        const unsigned char* __restrict__ xq, const int* __restrict__ cnt2,
        const unsigned int* __restrict__ epack, unsigned short* __restrict__ hb) {
    const int b = blockIdx.x * 8 + (threadIdx.x >> 5);
    const int l32 = threadIdx.x & 31;
    const int xoff = l32 * 8;
    const int s = b / N_NODES;
    const int node = b - s * N_NODES;

    int c = cnt2[b]; if (c > CAP) c = CAP;
    const unsigned int* ep = epack + (size_t)b * CAP;

    float a[8];
#pragma unroll
    for (int j = 0; j < 8; ++j) a[j] = 0.f;
    float sw = 0.f;

    int it = 0;
    for (; it + 3 < c; it += 4) {        // 4 independent 8B table loads in flight
        const uint4 pk = *(const uint4*)(ep + it);
        const uint2 u0 = *(const uint2*)(xq + ((size_t)(pk.x & 0xFFFFu) << 8) + xoff);
        const uint2 u1 = *(const uint2*)(xq + ((size_t)(pk.y & 0xFFFFu) << 8) + xoff);
        const uint2 u2 = *(const uint2*)(xq + ((size_t)(pk.z & 0xFFFFu) << 8) + xoff);
        const uint2 u3 = *(const uint2*)(xq + ((size_t)(pk.w & 0xFFFFu) << 8) + xoff);
        const float w0 = __uint_as_float(pk.x & 0xFFFF0000u);
        const float w1 = __uint_as_float(pk.y & 0xFFFF0000u);
        const float w2 = __uint_as_float(pk.z & 0xFFFF0000u);
        const float w3 = __uint_as_float(pk.w & 0xFFFF0000u);
        sw += w0 + w1 + w2 + w3;
#pragma unroll
        for (int j = 0; j < 4; ++j) {
            const int sh = 8 * j;
            a[j]     += w0 * (float)((u0.x >> sh) & 0xffu) + w1 * (float)((u1.x >> sh) & 0xffu)
                      + w2 * (float)((u2.x >> sh) & 0xffu) + w3 * (float)((u3.x >> sh) & 0xffu);
            a[4 + j] += w0 * (float)((u0.y >> sh) & 0xffu) + w1 * (float)((u1.y >> sh) & 0xffu)
                      + w2 * (float)((u2.y >> sh) & 0xffu) + w3 * (float)((u3.y >> sh) & 0xffu);
        }
    }
    for (; it < c; ++it) {               // <=3 cleanup iterations
        const unsigned int pe = ep[it];
        const uint2 u = *(const uint2*)(xq + ((size_t)(pe & 0xFFFFu) << 8) + xoff);
        const float wv = __uint_as_float(pe & 0xFFFF0000u);
        sw += wv;
#pragma unroll
        for (int j = 0; j < 4; ++j) {
            const int sh = 8 * j;
            a[j]     += wv * (float)((u.x >> sh) & 0xffu);
            a[4 + j] += wv * (float)((u.y >> sh) & 0xffu);
        }
    }

    ushort8 o;
    const float bias = 128.f * sw;
#pragma unroll
    for (int j = 0; j < 8; ++j) o[j] = f2bf(a[j] - bias);
    *(ushort8*)(hb + (size_t)node * KDIM + s * D_FEAT + xoff) = o;
}

// ---------------- gemm_h: BM=128 tile, LDS-staged B (unchanged, verified) ----------------
__global__ void __launch_bounds__(512) gemm_h(
        const unsigned short* __restrict__ hb, const unsigned short* __restrict__ wt,
        float* __restrict__ out) {
    __shared__ unsigned short bs[OUT_DIM][136];
    const int n0 = blockIdx.x * GM_ROWS;
    const int wid = threadIdx.x >> 6;
    const int lane = threadIdx.x & 63;
    const int cit = lane & 15;
    const int kgrp = (lane >> 4) * 8;
    const bool valid = (n0 + wid * 16) < N_NODES;
    const int arow_idx = valid ? (n0 + wid * 16 + cit) : 0;
    const short* arow = (const short*)hb + (size_t)arow_idx * KDIM + kgrp;

    f32x4 acc[16];
#pragma unroll
    for (int j = 0; j < 16; ++j) acc[j] = (f32x4){0.f, 0.f, 0.f, 0.f};

    for (int kc = 0; kc < 6; ++kc) {
        const int s = kc >> 1;
        const int kb = (kc & 1) * 128;
        if (kc) __syncthreads();
        for (int i = threadIdx.x; i < 4096; i += 512) {
            const int n = i >> 4;
            const int k8 = (i & 15) << 3;
            *(ushort8*)&bs[n][k8] =
                *(const ushort8*)(wt + ((size_t)s * OUT_DIM + n) * D_FEAT + kb + k8);
        }
        __syncthreads();

#pragma unroll
        for (int ks = 0; ks < 4; ++ks) {
            short8 av = *(const short8*)(arow + kc * 128 + ks * 32);
#pragma unroll
            for (int nt = 0; nt < 16; ++nt) {
                short8 bv = *(const short8*)&bs[nt * 16 + cit][ks * 32 + kgrp];
                acc[nt] = __builtin_amdgcn_mfma_f32_16x16x32_bf16(av, bv, acc[nt], 0, 0, 0);
            }
        }
    }

    if (valid) {
        const int rbase = (lane >> 4) * 4;
#pragma unroll
        for (int nt = 0; nt < 16; ++nt) {
            const int col = nt * 16 + cit;
#pragma unroll
            for (int r = 0; r < 4; ++r) {
                out[(size_t)(n0 + wid * 16 + rbase + r) * OUT_DIM + col] = acc[nt][r];
            }
        }
    }
}

extern "C" void kernel_launch(void* const* d_in, const int* in_sizes, int n_in,
                              void* d_out, int out_size, void* d_ws, size_t ws_size,
                              hipStream_t stream) {
    const float* x        = (const float*)d_in[0];
    const int*   edge_src = (const int*)d_in[1];
    const int*   edge_dst = (const int*)d_in[2];
    const float* edge_w   = (const float*)d_in[3];
    const float* W        = (const float*)d_in[4];
    float* out = (float*)d_out;

    char* ws = (char*)d_ws;
    unsigned int*   xq    = (unsigned int*)(ws);                 //  5,120,000 B
    float*          scl   = (float*)(ws + 5120000);              //     80,000 B
    unsigned short* wt    = (unsigned short*)(ws + 5200000);     //    393,216 B
    int*            cur8  = (int*)(ws + 5593216);                //  1,920,000 B (8 windows)
    int*            cnt2  = (int*)(ws + 7513216);                //    240,000 B
    unsigned int*   ep2   = (unsigned int*)(ws + 7753216);       // 15,360,000 B (CAP=64 compacted)
    unsigned int*   ep1   = (unsigned int*)(ws + 23113216);      // 30,720,000 B (8 win x CAPX=16)
    unsigned short* hb    = (unsigned short*)(ws + 23113216);    //   OVERLAY: ep1 dead after compact
    // total: 53,833,216 B

    hipMemsetAsync(cur8, 0, 1920000, stream);

    prep1<<<NB_X + NB_W, 256, 0, stream>>>(x, W, xq, scl, wt);
    fill_win<<<NB_F, 256, 0, stream>>>(edge_src, edge_dst, edge_w, scl, cur8, ep1);
    compact<<<NBUCKET / 8, 256, 0, stream>>>(cur8, ep1, cnt2, ep2);

    aggregate<<<NBUCKET / 8, 256, 0, stream>>>((const unsigned char*)xq, cnt2, ep2, hb);

    gemm_h<<<GM_BLOCKS, 512, 0, stream>>>(hb, wt, out);
}